// Round 7
// baseline (165.834 us; speedup 1.0000x reference)
//
#include <hip/hip_runtime.h>
#include <math.h>

#define B_SZ 16
#define K_PTS 4096
#define ALPHA 1.1f
#define NB 256
#define BIGF 3.0e38f
#define EPSZ 1e-3f

// ws layout (bytes): pts4 float4[B][4096] @0 (1 MiB); perm uint[B][4096] @1048576;
// bs uint[B][260] @1310720; hdr float[B][4] @1327360. total 1327616 B.
#define WS_PERM_OFF 1048576
#define WS_BS_OFF   1310720
#define WS_HDR_OFF  1327360
#define WS_NEEDED   1327616

__device__ __forceinline__ void insert2(float d, float& m0, float& m1) {
    m1 = __builtin_amdgcn_fmed3f(d, m0, m1);
    m0 = fminf(d, m0);
}
__device__ __forceinline__ void insert3(float d, float& m0, float& m1, float& m2) {
    m2 = __builtin_amdgcn_fmed3f(d, m1, m2);
    m1 = __builtin_amdgcn_fmed3f(d, m0, m1);
    m0 = fminf(d, m0);
}

// Setup: per batch, counting-sort points into NB z-bins. Writes binned float4
// (x,y,z,||x||^2), permutation (binned pos -> orig idx), bin starts, header
// (zmin, w, invw). Scatter order within a bin is nondeterministic (atomics)
// but downstream results are order-independent (exact min-set selection).
__global__ __launch_bounds__(1024) void sor_setup(
    const float* __restrict__ x, float4* __restrict__ pts4,
    unsigned* __restrict__ perm, unsigned* __restrict__ bsg,
    float* __restrict__ hdr)
{
    __shared__ unsigned hist[NB];
    __shared__ unsigned cur[NB];
    __shared__ unsigned bs[NB + 1];
    __shared__ float redmin[16], redmax[16];
    __shared__ float sh_zmin, sh_invw;

    const int b = blockIdx.x;
    const int tid = threadIdx.x;
    const float* xb = x + (size_t)b * K_PTS * 3;

    float z[4];
    float zmn = BIGF, zmx = -BIGF;
    #pragma unroll
    for (int k = 0; k < 4; ++k) {
        z[k] = xb[(tid + k * 1024) * 3 + 2];
        zmn = fminf(zmn, z[k]);
        zmx = fmaxf(zmx, z[k]);
    }
    #pragma unroll
    for (int off = 32; off > 0; off >>= 1) {
        zmn = fminf(zmn, __shfl_down(zmn, off, 64));
        zmx = fmaxf(zmx, __shfl_down(zmx, off, 64));
    }
    if ((tid & 63) == 0) { redmin[tid >> 6] = zmn; redmax[tid >> 6] = zmx; }
    if (tid < NB) hist[tid] = 0;
    __syncthreads();
    if (tid == 0) {
        float mn = redmin[0], mx = redmax[0];
        for (int wv = 1; wv < 16; ++wv) {
            mn = fminf(mn, redmin[wv]);
            mx = fmaxf(mx, redmax[wv]);
        }
        const float rng = fmaxf(mx - mn, 1e-6f);
        const float w = rng * (1.0f / NB);
        sh_zmin = mn;
        sh_invw = 1.0f / w;
        hdr[b * 4 + 0] = mn;
        hdr[b * 4 + 1] = w;
        hdr[b * 4 + 2] = 1.0f / w;
    }
    __syncthreads();
    const float zmin = sh_zmin, invw = sh_invw;

    int kb[4];
    #pragma unroll
    for (int k = 0; k < 4; ++k) {
        int kk = (int)((z[k] - zmin) * invw);
        kk = min(NB - 1, max(0, kk));
        kb[k] = kk;
        atomicAdd(&hist[kk], 1u);
    }
    __syncthreads();
    if (tid == 0) {
        unsigned acc = 0;
        bs[0] = 0;
        for (int k2 = 0; k2 < NB; ++k2) { acc += hist[k2]; bs[k2 + 1] = acc; }
    }
    if (tid < NB) cur[tid] = 0;
    __syncthreads();
    if (tid <= NB) bsg[b * 260 + tid] = bs[tid];

    #pragma unroll
    for (int k = 0; k < 4; ++k) {
        const int p = tid + k * 1024;
        const int kk = kb[k];
        const unsigned pos = bs[kk] + atomicAdd(&cur[kk], 1u);
        const float a0 = xb[p * 3 + 0];
        const float a1 = xb[p * 3 + 1];
        const float a2 = z[k];
        pts4[(size_t)b * K_PTS + pos] = make_float4(a0, a1, a2, a0 * a0 + a1 * a1 + a2 * a2);
        perm[(size_t)b * K_PTS + pos] = (unsigned)p;
    }
}

// Exact pruned 2NN search. grid (16,16) = 256 blocks x 512 thr. Each block:
// 256 consecutive binned points; waves 0-3 walk UP (j >= ip, incl self,
// top-3), waves 4-7 walk DOWN (j < ip, top-2). Wave-uniform candidate stream
// (LDS broadcast reads); per-lane skip predicate avoids double counting.
// Lane releases when the next bin's edge gap^2 exceeds its running bound
// (m2+wi up / m1+wi down) - conservative-exact with EPSZ margin for binning
// float rounding. Shifted distance d' = -2<xi,xj> + ||xj||^2, identical fma
// chain to the brute-force rounds (mask-identical values).
__global__ __launch_bounds__(512) void sor_search(
    const float4* __restrict__ pts4, const unsigned* __restrict__ perm,
    const unsigned* __restrict__ bsg, const float* __restrict__ hdr,
    float* __restrict__ value)
{
    __shared__ float4 pts[K_PTS];      // 64 KiB
    __shared__ unsigned bs[NB + 1];
    __shared__ float2 dnres[256];

    const int b = blockIdx.y;
    const int blk = blockIdx.x;
    const int tid = threadIdx.x;

    #pragma unroll
    for (int it = 0; it < 8; ++it) {
        const int idx = tid + it * 512;
        pts[idx] = pts4[(size_t)b * K_PTS + idx];
    }
    if (tid <= NB) bs[tid] = bsg[b * 260 + tid];
    __syncthreads();

    const float zmin = hdr[b * 4 + 0];
    const float w    = hdr[b * 4 + 1];
    const float invw = hdr[b * 4 + 2];

    const int lane = tid & 63;
    const int role = tid >> 8;            // 0 = up, 1 = down
    const int wv = (tid >> 6) & 3;
    const int ip = blk * 256 + wv * 64 + lane;

    const float4 pi = pts[ip];
    const float wi = pi.w, zi = pi.z;
    const float xi2 = -2.0f * pi.x, yi2 = -2.0f * pi.y, zi2 = -2.0f * pi.z;
    int k_i = (int)((zi - zmin) * invw);
    k_i = min(NB - 1, max(0, k_i));

    float m0 = BIGF, m1 = BIGF, m2 = BIGF;

    if (role == 0) {
        const int kk = __shfl(k_i, 0, 64);      // bin of wave's first point
        int j = blk * 256 + wv * 64;            // jbase
        bool act = true;
        for (int k = kk; k < NB; ++k) {
            const float edge = zmin + (float)k * w;
            const float gap = fmaxf(edge - zi - EPSZ, 0.0f);
            act = act && (gap * gap <= m2 + wi);
            if (__ballot(act) == 0ull) break;
            const int e = __builtin_amdgcn_readfirstlane((int)bs[k + 1]);
            for (; j < e; ++j) {
                const float4 pj = pts[j];       // broadcast read
                float t = fmaf(zi2, pj.z, pj.w);
                t = fmaf(yi2, pj.y, t);
                float d = fmaf(xi2, pj.x, t);
                d = (j >= ip) ? d : BIGF;       // up-side only (incl self)
                insert3(d, m0, m1, m2);
            }
        }
    } else {
        const int kk = __shfl(k_i, 62, 64);     // bin of highest down candidate
        int j = blk * 256 + wv * 64 + 62;
        bool act = true;
        for (int k = kk; k >= 0; --k) {
            const float edge = zmin + (float)(k + 1) * w;
            const float gap = fmaxf(zi - edge - EPSZ, 0.0f);
            act = act && (gap * gap <= m1 + wi);
            if (__ballot(act) == 0ull) break;
            const int s = __builtin_amdgcn_readfirstlane((int)bs[k]);
            for (; j >= s; --j) {
                const float4 pj = pts[j];       // broadcast read
                float t = fmaf(zi2, pj.z, pj.w);
                t = fmaf(yi2, pj.y, t);
                float d = fmaf(xi2, pj.x, t);
                d = (j < ip) ? d : BIGF;        // down-side only
                insert2(d, m0, m1);
            }
        }
        dnres[wv * 64 + lane] = make_float2(m0, m1);
    }
    __syncthreads();
    if (role == 0) {
        const float2 dn = dnres[wv * 64 + lane];
        // self = global min = up's m0 (d'_self = -wi strictly smallest).
        // 2NN = two smallest of {up.m1, up.m2, dn.m0, dn.m1}.
        float M0 = BIGF, M1 = BIGF;
        insert2(m1, M0, M1);
        insert2(m2, M0, M1);
        insert2(dn.x, M0, M1);
        insert2(dn.y, M0, M1);
        const unsigned orig = perm[(size_t)b * K_PTS + ip];
        value[(size_t)b * K_PTS + orig] = ((M0 + wi) + (M1 + wi)) * 0.5f;
    }
}

// One block per batch: mean/std(ddof=1) -> threshold -> mask + zeroed points.
__global__ __launch_bounds__(1024) void sor_mask_kernel(
    const float* __restrict__ x, float* __restrict__ out)
{
    const int b = blockIdx.x;
    const int tid = threadIdx.x;
    float* value = out + (size_t)B_SZ * K_PTS * 3;
    float* selpc = out;

    __shared__ float red[16];
    __shared__ float sh_mean, sh_thr;

    float v[4];
    float s = 0.0f;
    #pragma unroll
    for (int k = 0; k < 4; ++k) {
        v[k] = value[b * K_PTS + tid + k * 1024];
        s += v[k];
    }
    #pragma unroll
    for (int off = 32; off > 0; off >>= 1) s += __shfl_down(s, off, 64);
    if ((tid & 63) == 0) red[tid >> 6] = s;
    __syncthreads();
    if (tid == 0) {
        float t = 0.0f;
        for (int wv = 0; wv < 16; ++wv) t += red[wv];
        sh_mean = t * (1.0f / (float)K_PTS);
    }
    __syncthreads();
    const float mean = sh_mean;

    float q = 0.0f;
    #pragma unroll
    for (int k = 0; k < 4; ++k) { float dv = v[k] - mean; q += dv * dv; }
    #pragma unroll
    for (int off = 32; off > 0; off >>= 1) q += __shfl_down(q, off, 64);
    if ((tid & 63) == 0) red[tid >> 6] = q;
    __syncthreads();
    if (tid == 0) {
        float t = 0.0f;
        for (int wv = 0; wv < 16; ++wv) t += red[wv];
        sh_thr = mean + ALPHA * sqrtf(t / (float)(K_PTS - 1));
    }
    __syncthreads();
    const float thr = sh_thr;

    #pragma unroll
    for (int k = 0; k < 4; ++k) {
        const int i = tid + k * 1024;
        const bool keep = v[k] <= thr;
        value[b * K_PTS + i] = keep ? 1.0f : 0.0f;
        const size_t base = ((size_t)b * K_PTS + i) * 3;
        float x0 = x[base + 0];
        float x1 = x[base + 1];
        float x2 = x[base + 2];
        selpc[base + 0] = keep ? x0 : 0.0f;
        selpc[base + 1] = keep ? x1 : 0.0f;
        selpc[base + 2] = keep ? x2 : 0.0f;
    }
}

// ---- Fallback (round-1 structure) used only if d_ws is too small ----
__global__ __launch_bounds__(256) void sor_value_kernel(
    const float* __restrict__ x, float* __restrict__ value)
{
    __shared__ float4 pts[K_PTS];
    const int b = blockIdx.y;
    const float* xb = x + (size_t)b * K_PTS * 3;
    for (int p = threadIdx.x; p < K_PTS; p += 256) {
        float a0 = xb[p * 3 + 0];
        float a1 = xb[p * 3 + 1];
        float a2 = xb[p * 3 + 2];
        pts[p] = make_float4(a0, a1, a2, a0 * a0 + a1 * a1 + a2 * a2);
    }
    __syncthreads();
    const int i = blockIdx.x * 256 + threadIdx.x;
    const float4 pi = pts[i];
    float m0 = BIGF, m1 = BIGF, m2 = BIGF;
    #pragma unroll 8
    for (int j = 0; j < K_PTS; ++j) {
        float4 pj = pts[j];
        float dot = pi.x * pj.x + pi.y * pj.y + pi.z * pj.z;
        float d = (pi.w - 2.0f * dot) + pj.w;
        insert3(d, m0, m1, m2);
    }
    value[b * K_PTS + i] = 0.5f * (m1 + m2);
}

extern "C" void kernel_launch(void* const* d_in, const int* in_sizes, int n_in,
                              void* d_out, int out_size, void* d_ws, size_t ws_size,
                              hipStream_t stream)
{
    const float* x = (const float*)d_in[0];
    float* out = (float*)d_out;
    float* value = out + (size_t)B_SZ * K_PTS * 3;

    if (ws_size >= (size_t)WS_NEEDED) {
        float4* pts4 = (float4*)d_ws;
        unsigned* perm = (unsigned*)((char*)d_ws + WS_PERM_OFF);
        unsigned* bsg = (unsigned*)((char*)d_ws + WS_BS_OFF);
        float* hdr = (float*)((char*)d_ws + WS_HDR_OFF);

        sor_setup<<<B_SZ, 1024, 0, stream>>>(x, pts4, perm, bsg, hdr);
        dim3 gS(K_PTS / 256, B_SZ);   // (16,16) = 256 blocks
        sor_search<<<gS, 512, 0, stream>>>(pts4, perm, bsg, hdr, value);
    } else {
        dim3 g1(K_PTS / 256, B_SZ);
        sor_value_kernel<<<g1, 256, 0, stream>>>(x, value);
    }
    sor_mask_kernel<<<B_SZ, 1024, 0, stream>>>(x, out);
}

// Round 8
// 66.875 us; speedup vs baseline: 2.4798x; 2.4798x over previous
//
#include <hip/hip_runtime.h>
#include <math.h>

#define B_SZ 16
#define K_PTS 4096
#define ALPHA 1.1f
#define NB 256
#define BIGF 3.0e38f
#define EPSZ 1e-3f

// ws layout (bytes): pts4 float4[B][4096] @0 (1 MiB);
// perm uint[B][4096] @1048576; binb uint[B][4096] @1310720;
// hdr float[B][4] @1572864. total 1573120 B.
#define WS_PERM_OFF 1048576
#define WS_BINB_OFF 1310720
#define WS_HDR_OFF  1572864
#define WS_NEEDED   1573120

__device__ __forceinline__ void insert2(float d, float& m0, float& m1) {
    m1 = __builtin_amdgcn_fmed3f(d, m0, m1);
    m0 = fminf(d, m0);
}
__device__ __forceinline__ void insert3(float d, float& m0, float& m1, float& m2) {
    m2 = __builtin_amdgcn_fmed3f(d, m1, m2);
    m1 = __builtin_amdgcn_fmed3f(d, m0, m1);
    m0 = fminf(d, m0);
}

// Setup: per batch, counting-sort points into NB z-bins. Writes binned float4
// (x,y,z,||x||^2), permutation, per-position bin index, header (zmin,w,invw).
// Within-bin scatter order is nondeterministic (atomics) but all downstream
// results are order-independent exact min-set selections.
__global__ __launch_bounds__(1024) void sor_setup(
    const float* __restrict__ x, float4* __restrict__ pts4,
    unsigned* __restrict__ perm, unsigned* __restrict__ binb,
    float* __restrict__ hdr)
{
    __shared__ unsigned hist[NB];
    __shared__ unsigned cur[NB];
    __shared__ unsigned bs[NB + 1];
    __shared__ float redmin[16], redmax[16];
    __shared__ float sh_zmin, sh_invw;

    const int b = blockIdx.x;
    const int tid = threadIdx.x;
    const float* xb = x + (size_t)b * K_PTS * 3;

    float z[4];
    float zmn = BIGF, zmx = -BIGF;
    #pragma unroll
    for (int k = 0; k < 4; ++k) {
        z[k] = xb[(tid + k * 1024) * 3 + 2];
        zmn = fminf(zmn, z[k]);
        zmx = fmaxf(zmx, z[k]);
    }
    #pragma unroll
    for (int off = 32; off > 0; off >>= 1) {
        zmn = fminf(zmn, __shfl_down(zmn, off, 64));
        zmx = fmaxf(zmx, __shfl_down(zmx, off, 64));
    }
    if ((tid & 63) == 0) { redmin[tid >> 6] = zmn; redmax[tid >> 6] = zmx; }
    if (tid < NB) hist[tid] = 0;
    __syncthreads();
    if (tid == 0) {
        float mn = redmin[0], mx = redmax[0];
        for (int wv = 1; wv < 16; ++wv) {
            mn = fminf(mn, redmin[wv]);
            mx = fmaxf(mx, redmax[wv]);
        }
        const float rng = fmaxf(mx - mn, 1e-6f);
        const float w = rng * (1.0f / NB);
        sh_zmin = mn;
        sh_invw = 1.0f / w;
        hdr[b * 4 + 0] = mn;
        hdr[b * 4 + 1] = w;
        hdr[b * 4 + 2] = 1.0f / w;
    }
    __syncthreads();
    const float zmin = sh_zmin, invw = sh_invw;

    int kb[4];
    #pragma unroll
    for (int k = 0; k < 4; ++k) {
        int kk = (int)((z[k] - zmin) * invw);
        kk = min(NB - 1, max(0, kk));
        kb[k] = kk;
        atomicAdd(&hist[kk], 1u);
    }
    __syncthreads();
    if (tid == 0) {
        unsigned acc = 0;
        bs[0] = 0;
        for (int k2 = 0; k2 < NB; ++k2) { acc += hist[k2]; bs[k2 + 1] = acc; }
    }
    if (tid < NB) cur[tid] = 0;
    __syncthreads();

    #pragma unroll
    for (int k = 0; k < 4; ++k) {
        const int p = tid + k * 1024;
        const int kk = kb[k];
        const unsigned pos = bs[kk] + atomicAdd(&cur[kk], 1u);
        const float a0 = xb[p * 3 + 0];
        const float a1 = xb[p * 3 + 1];
        const float a2 = z[k];
        pts4[(size_t)b * K_PTS + pos] = make_float4(a0, a1, a2, a0 * a0 + a1 * a1 + a2 * a2);
        perm[(size_t)b * K_PTS + pos] = (unsigned)p;
        binb[(size_t)b * K_PTS + pos] = (unsigned)kk;
    }
}

// Exact pruned 2NN search. grid (16 seg, 16 b) = 256 blocks x 512 thr.
// Segment = 256 consecutive z-sorted points. Waves 0-3: UP role (j >= i,
// incl self, top-3); waves 4-7: DOWN role (j < i, top-2). Both roles run
// concurrently; merge via LDS after one barrier. Candidate stream = static
// 64-point groups (fully unrollable, broadcast LDS reads); release check
// between groups via conservative bin-edge bounds zfl/zcl (EPSZ absorbs
// binning fp slack; releases can only be late, never early -> exact).
__global__ __launch_bounds__(512) void sor_search(
    const float4* __restrict__ pts4, const unsigned* __restrict__ perm,
    const unsigned* __restrict__ binb, const float* __restrict__ hdr,
    float* __restrict__ value)
{
    __shared__ float4 pts[K_PTS];      // 64 KiB
    __shared__ float zfl[64], zcl[64];
    __shared__ float2 dnres[256];

    const int b = blockIdx.y;
    const int s = blockIdx.x;          // segment 0..15
    const int tid = threadIdx.x;

    #pragma unroll
    for (int it = 0; it < 8; ++it) {
        const int idx = tid + it * 512;
        pts[idx] = pts4[(size_t)b * K_PTS + idx];
    }
    const float zmin = hdr[b * 4 + 0];
    const float w    = hdr[b * 4 + 1];
    if (tid < 64) {
        // all points at position >= g*64 have z >= zfl[g];
        // all points at position <= g*64+63 have z <= zcl[g] (monotone in g).
        zfl[tid] = zmin + (float)binb[(size_t)b * K_PTS + tid * 64] * w;
        zcl[tid] = zmin + (float)(binb[(size_t)b * K_PTS + tid * 64 + 63] + 1u) * w;
    }
    __syncthreads();

    const int lane = tid & 63;
    const int wv = tid >> 6;
    const int role = wv >> 2;          // 0 = up, 1 = down
    const int wq = wv & 3;
    const int i = s * 256 + wq * 64 + lane;
    const int g0 = s * 4 + wq;         // group containing i

    const float4 pi = pts[i];
    const float wi = pi.w, zi = pi.z;
    const float xi2 = -2.0f * pi.x, yi2 = -2.0f * pi.y, zi2 = -2.0f * pi.z;

    float um1 = 0.0f, um2 = 0.0f;      // up results carried to merge

    if (role == 0) {
        // ---- UP: j >= i, top-3 including self ----
        float m0 = BIGF, m1 = BIGF, m2 = BIGF;
        {   // own group, guarded
            const int jb = g0 * 64;
            #pragma unroll 16
            for (int jj = 0; jj < 64; ++jj) {
                const float4 pj = pts[jb + jj];
                float t = fmaf(zi2, pj.z, pj.w);
                t = fmaf(yi2, pj.y, t);
                float d = fmaf(xi2, pj.x, t);
                d = (jb + jj >= i) ? d : BIGF;
                insert3(d, m0, m1, m2);
            }
        }
        for (int g = g0 + 1; g < 64; ++g) {
            const float gap = fmaxf(zfl[g] - zi - EPSZ, 0.0f);
            const bool act = (gap * gap <= m2 + wi);
            if (__ballot(act) == 0ull) break;
            const int jb = g * 64;
            #pragma unroll 16
            for (int jj = 0; jj < 64; ++jj) {
                const float4 pj = pts[jb + jj];
                float t = fmaf(zi2, pj.z, pj.w);
                t = fmaf(yi2, pj.y, t);
                float d = fmaf(xi2, pj.x, t);
                insert3(d, m0, m1, m2);
            }
        }
        um1 = m1; um2 = m2;            // m0 == self (strict min), dropped
    } else {
        // ---- DOWN: j < i, top-2 ----
        float m0 = BIGF, m1 = BIGF;
        {   // own group, guarded
            const int jb = g0 * 64;
            #pragma unroll 16
            for (int jj = 0; jj < 64; ++jj) {
                const float4 pj = pts[jb + jj];
                float t = fmaf(zi2, pj.z, pj.w);
                t = fmaf(yi2, pj.y, t);
                float d = fmaf(xi2, pj.x, t);
                d = (jb + jj < i) ? d : BIGF;
                insert2(d, m0, m1);
            }
        }
        for (int g = g0 - 1; g >= 0; --g) {
            const float gap = fmaxf(zi - zcl[g] - EPSZ, 0.0f);
            const bool act = (gap * gap <= m1 + wi);
            if (__ballot(act) == 0ull) break;
            const int jb = g * 64;
            #pragma unroll 16
            for (int jj = 0; jj < 64; ++jj) {
                const float4 pj = pts[jb + jj];
                float t = fmaf(zi2, pj.z, pj.w);
                t = fmaf(yi2, pj.y, t);
                float d = fmaf(xi2, pj.x, t);
                insert2(d, m0, m1);
            }
        }
        dnres[tid & 255] = make_float2(m0, m1);
    }
    __syncthreads();

    if (role == 0) {
        const float2 dn = dnres[tid & 255];
        // 2NN = two smallest of {up.m1, up.m2, dn.m0, dn.m1}
        float M0 = BIGF, M1 = BIGF;
        insert2(um1, M0, M1);
        insert2(um2, M0, M1);
        insert2(dn.x, M0, M1);
        insert2(dn.y, M0, M1);
        const unsigned orig = perm[(size_t)b * K_PTS + i];
        value[(size_t)b * K_PTS + orig] = ((M0 + wi) + (M1 + wi)) * 0.5f;
    }
}

// One block per batch: mean/std(ddof=1) -> threshold -> mask + zeroed points.
__global__ __launch_bounds__(1024) void sor_mask_kernel(
    const float* __restrict__ x, float* __restrict__ out)
{
    const int b = blockIdx.x;
    const int tid = threadIdx.x;
    float* value = out + (size_t)B_SZ * K_PTS * 3;
    float* selpc = out;

    __shared__ float red[16];
    __shared__ float sh_mean, sh_thr;

    float v[4];
    float s = 0.0f;
    #pragma unroll
    for (int k = 0; k < 4; ++k) {
        v[k] = value[b * K_PTS + tid + k * 1024];
        s += v[k];
    }
    #pragma unroll
    for (int off = 32; off > 0; off >>= 1) s += __shfl_down(s, off, 64);
    if ((tid & 63) == 0) red[tid >> 6] = s;
    __syncthreads();
    if (tid == 0) {
        float t = 0.0f;
        for (int wv = 0; wv < 16; ++wv) t += red[wv];
        sh_mean = t * (1.0f / (float)K_PTS);
    }
    __syncthreads();
    const float mean = sh_mean;

    float q = 0.0f;
    #pragma unroll
    for (int k = 0; k < 4; ++k) { float dv = v[k] - mean; q += dv * dv; }
    #pragma unroll
    for (int off = 32; off > 0; off >>= 1) q += __shfl_down(q, off, 64);
    if ((tid & 63) == 0) red[tid >> 6] = q;
    __syncthreads();
    if (tid == 0) {
        float t = 0.0f;
        for (int wv = 0; wv < 16; ++wv) t += red[wv];
        sh_thr = mean + ALPHA * sqrtf(t / (float)(K_PTS - 1));
    }
    __syncthreads();
    const float thr = sh_thr;

    #pragma unroll
    for (int k = 0; k < 4; ++k) {
        const int i = tid + k * 1024;
        const bool keep = v[k] <= thr;
        value[b * K_PTS + i] = keep ? 1.0f : 0.0f;
        const size_t base = ((size_t)b * K_PTS + i) * 3;
        float x0 = x[base + 0];
        float x1 = x[base + 1];
        float x2 = x[base + 2];
        selpc[base + 0] = keep ? x0 : 0.0f;
        selpc[base + 1] = keep ? x1 : 0.0f;
        selpc[base + 2] = keep ? x2 : 0.0f;
    }
}

// ---- Fallback (round-1 structure) used only if d_ws is too small ----
__global__ __launch_bounds__(256) void sor_value_kernel(
    const float* __restrict__ x, float* __restrict__ value)
{
    __shared__ float4 pts[K_PTS];
    const int b = blockIdx.y;
    const float* xb = x + (size_t)b * K_PTS * 3;
    for (int p = threadIdx.x; p < K_PTS; p += 256) {
        float a0 = xb[p * 3 + 0];
        float a1 = xb[p * 3 + 1];
        float a2 = xb[p * 3 + 2];
        pts[p] = make_float4(a0, a1, a2, a0 * a0 + a1 * a1 + a2 * a2);
    }
    __syncthreads();
    const int i = blockIdx.x * 256 + threadIdx.x;
    const float4 pi = pts[i];
    float m0 = BIGF, m1 = BIGF, m2 = BIGF;
    #pragma unroll 8
    for (int j = 0; j < K_PTS; ++j) {
        float4 pj = pts[j];
        float dot = pi.x * pj.x + pi.y * pj.y + pi.z * pj.z;
        float d = (pi.w - 2.0f * dot) + pj.w;
        insert3(d, m0, m1, m2);
    }
    value[b * K_PTS + i] = 0.5f * (m1 + m2);
}

extern "C" void kernel_launch(void* const* d_in, const int* in_sizes, int n_in,
                              void* d_out, int out_size, void* d_ws, size_t ws_size,
                              hipStream_t stream)
{
    const float* x = (const float*)d_in[0];
    float* out = (float*)d_out;
    float* value = out + (size_t)B_SZ * K_PTS * 3;

    if (ws_size >= (size_t)WS_NEEDED) {
        float4* pts4 = (float4*)d_ws;
        unsigned* perm = (unsigned*)((char*)d_ws + WS_PERM_OFF);
        unsigned* binb = (unsigned*)((char*)d_ws + WS_BINB_OFF);
        float* hdr = (float*)((char*)d_ws + WS_HDR_OFF);

        sor_setup<<<B_SZ, 1024, 0, stream>>>(x, pts4, perm, binb, hdr);
        dim3 gS(K_PTS / 256, B_SZ);   // (16,16) = 256 blocks
        sor_search<<<gS, 512, 0, stream>>>(pts4, perm, binb, hdr, value);
    } else {
        dim3 g1(K_PTS / 256, B_SZ);
        sor_value_kernel<<<g1, 256, 0, stream>>>(x, value);
    }
    sor_mask_kernel<<<B_SZ, 1024, 0, stream>>>(x, out);
}